// Round 6
// baseline (477.253 us; speedup 1.0000x reference)
//
#include <hip/hip_runtime.h>

#define NBATCH 8
#define NROWS 2048
#define MDIM 128
#define NITER 50
#define RSTR 132   // main-loop row stride (floats): 132%32=4 -> conflict-free b128 phases
#define PSTR 65    // staging stride for Q^T [d][r]: 4-way write conflicts, cf reads
#define BUFSZ 8448 // 64*132 floats per rhs buffer

// ---------------------------------------------------------------------------
// mk_m64: M = I + 2*Vs*Vs^T (f64), X0 = 2I - M.
// grid 128 = 8b x 16 (32x32 tiles). Per-element fma chain identical to R2-R5.
// ---------------------------------------------------------------------------
__global__ __launch_bounds__(256) void mk_m64(const float* __restrict__ V,
                                              double* __restrict__ M,
                                              double* __restrict__ X0) {
  __shared__ double sA[32][130];
  __shared__ double sB[32][130];
  const int b = blockIdx.x >> 4, t = blockIdx.x & 15;
  const int i0 = (t >> 2) << 5, j0 = (t & 3) << 5;
  const float* Vb = V + b * MDIM * MDIM;
  const int tid = threadIdx.x;
  const double S = 1.0 / 128.0;
  for (int idx = tid; idx < 1024; idx += 256) {
    const int r = idx >> 5, c4 = (idx & 31) << 2;
    float4 v = *(const float4*)(Vb + (i0 + r) * MDIM + c4);
    sA[r][c4 + 0] = v.x * S; sA[r][c4 + 1] = v.y * S;
    sA[r][c4 + 2] = v.z * S; sA[r][c4 + 3] = v.w * S;
    float4 w = *(const float4*)(Vb + (j0 + r) * MDIM + c4);
    sB[r][c4 + 0] = w.x * S; sB[r][c4 + 1] = w.y * S;
    sB[r][c4 + 2] = w.z * S; sB[r][c4 + 3] = w.w * S;
  }
  __syncthreads();
  const int tx = tid & 15, ty = tid >> 4;
  double acc[2][2] = {};
  for (int k = 0; k < 128; ++k) {
    double a0 = sA[ty * 2 + 0][k], a1 = sA[ty * 2 + 1][k];
    double b0 = sB[tx * 2 + 0][k], b1 = sB[tx * 2 + 1][k];
    acc[0][0] = fma(a0, b0, acc[0][0]); acc[0][1] = fma(a0, b1, acc[0][1]);
    acc[1][0] = fma(a1, b0, acc[1][0]); acc[1][1] = fma(a1, b1, acc[1][1]);
  }
  double* Mb = M + b * 16384;
  double* Xb = X0 + b * 16384;
#pragma unroll
  for (int i = 0; i < 2; ++i)
#pragma unroll
    for (int j = 0; j < 2; ++j) {
      const int gi = i0 + ty * 2 + i, gj = j0 + tx * 2 + j;
      const double diag = (gi == gj) ? 1.0 : 0.0;
      const double mv = 2.0 * acc[i][j] + diag;
      Mb[gi * 128 + gj] = mv;
      Xb[gi * 128 + gj] = 2.0 * diag - mv;
    }
}

// ---------------------------------------------------------------------------
// ns_gemm64: C = A*B (B symmetric, read rows). mode1: C = 2*Xc - A*B.
// grid 128. Per-element fma chain identical to R2-R5.
// ---------------------------------------------------------------------------
__global__ __launch_bounds__(256) void ns_gemm64(const double* __restrict__ A,
                                                 const double* __restrict__ B,
                                                 double* __restrict__ C,
                                                 const double* __restrict__ Xc,
                                                 int mode) {
  __shared__ double sA[32][130];
  __shared__ double sB[32][130];
  const int b = blockIdx.x >> 4, t = blockIdx.x & 15;
  const int i0 = (t >> 2) << 5, j0 = (t & 3) << 5;
  const double* Ab = A + b * 16384;
  const double* Bb = B + b * 16384;
  const int tid = threadIdx.x;
  for (int idx = tid; idx < 2048; idx += 256) {
    const int r = idx >> 6, c2 = (idx & 63) << 1;
    *(double2*)&sA[r][c2] = *(const double2*)(Ab + (i0 + r) * 128 + c2);
    *(double2*)&sB[r][c2] = *(const double2*)(Bb + (j0 + r) * 128 + c2);
  }
  __syncthreads();
  const int tx = tid & 15, ty = tid >> 4;
  double acc[2][2] = {};
  for (int k = 0; k < 128; ++k) {
    double a0 = sA[ty * 2 + 0][k], a1 = sA[ty * 2 + 1][k];
    double b0 = sB[tx * 2 + 0][k], b1 = sB[tx * 2 + 1][k];
    acc[0][0] = fma(a0, b0, acc[0][0]); acc[0][1] = fma(a0, b1, acc[0][1]);
    acc[1][0] = fma(a1, b0, acc[1][0]); acc[1][1] = fma(a1, b1, acc[1][1]);
  }
  double* Cb = C + b * 16384;
  const double* Xcb = Xc + b * 16384;
#pragma unroll
  for (int i = 0; i < 2; ++i)
#pragma unroll
    for (int j = 0; j < 2; ++j) {
      const int gi = i0 + ty * 2 + i, gj = j0 + tx * 2 + j;
      double v = acc[i][j];
      if (mode != 0) v = 2.0 * Xcb[gi * 128 + gj] - v;
      Cb[gi * 128 + gj] = v;
    }
}

// ---------------------------------------------------------------------------
// prep_aux: Wt = fp32(I - Minv) in tiled layout Wt[cg][j][8] (cg = col/8, 4 KB
// contiguous per cg -> sequential s_load_dwordx16 stream in the main loop);
// VsT64[d][m] = f64 V[m][d]/128.   Same bits as R5's W -> identical trajectory.
// ---------------------------------------------------------------------------
__global__ __launch_bounds__(256) void prep_aux(const double* __restrict__ Minv,
                                                const float* __restrict__ V,
                                                float* __restrict__ Wt,
                                                double* __restrict__ VsT64) {
  const int b = blockIdx.x >> 3, ch = blockIdx.x & 7;
  const double* Mb = Minv + b * 16384;
  const float* Vb = V + b * 16384;
  float* Wb = Wt + b * 16384;
  double* Tb = VsT64 + b * 16384;
  const int base = ch * 2048;
  for (int k = threadIdx.x; k < 2048; k += 256) {
    const int idx = base + k;
    const int j = idx >> 7, col = idx & 127;
    const int cg = col >> 3, c = col & 7;
    const double diag = (j == col) ? 1.0 : 0.0;
    Wb[cg * 1024 + j * 8 + c] = (float)(diag - Mb[idx]);
    Tb[idx] = (double)Vb[col * 128 + j] * (1.0 / 128.0);
  }
}

// ---------------------------------------------------------------------------
// admm_corr: persistent ADMM, f64 state + fp32 correction GEMM.
// grid 256; b = blockIdx&7 (XCD-aligned). 1024 threads = 16 waves (4/SIMD).
// lane = row; wave w -> cols c0 = 8w.  x = Minv r = r - W r.
// R6: (1) W in tiled layout -> contiguous 4 KB scalar stream per wave;
//     (2) double-buffered rhs -> ONE barrier per iteration;
//     (3) staging pad stride 65 (scatter conflicts 32-way -> 4-way).
// All per-element fma chains identical to R5 -> bit-identical trajectory.
// LDS: sR 2x33 KB + sCnt 4 KB = 70 KB (1 block/CU).
// ---------------------------------------------------------------------------
__global__ __launch_bounds__(1024, 4) void admm_corr(const float* __restrict__ Q,
                                                     const float* __restrict__ V,
                                                     const float* __restrict__ Wt,
                                                     const double* __restrict__ VsT64,
                                                     float* __restrict__ out) {
  __shared__ float sR[2 * BUFSZ];   // loop: [row][j] stride 132, dbuf; prologue: [d][r] stride 65
  __shared__ float sCnt[16 * 64];
  const int tid = threadIdx.x;
  const int b = blockIdx.x & 7;          // XCD id
  const int n0 = (blockIdx.x >> 3) << 6;
  const int lane = tid & 63;
  const int w = tid >> 6;                // 0..15
  const int c0 = w << 3;
  const int c0u = __builtin_amdgcn_readfirstlane(c0);
  const float* Qb = Q + ((size_t)(b * NROWS + n0)) * MDIM;
  const float* Wtw = Wt + b * 16384 + (c0u << 7);        // 4 KB contiguous: [j][8]
  const double* Vtc = VsT64 + b * 16384 + c0u;
  const float* Vc = V + b * 16384 + c0u;
  float* outb = out + ((size_t)(b * NROWS + n0)) * MDIM;

  // ---- stage Q^T (f32): sR[d*65 + r] = Q[n0+r][d]   (staging overlay, 8320 floats)
  for (int idx = tid; idx < 2048; idx += 1024) {
    const int r = idx >> 5, d4 = (idx & 31) << 2;
    const float4 q = *(const float4*)(Qb + r * 128 + d4);
    sR[(d4 + 0) * PSTR + r] = q.x;
    sR[(d4 + 1) * PSTR + r] = q.y;
    sR[(d4 + 2) * PSTR + r] = q.z;
    sR[(d4 + 3) * PSTR + r] = q.w;
  }
  __syncthreads();

  // ---- P = -2 Q Vs^T + lam/m   (f64, same fma chain as R5 -> bit-identical)
  double p[8];
#pragma unroll
  for (int c = 0; c < 8; ++c) p[c] = 0.0;
  for (int d = 0; d < 128; ++d) {
    const double a = (double)sR[d * PSTR + lane];
    const double* vt = Vtc + d * 128;
#pragma unroll
    for (int c = 0; c < 8; ++c) p[c] = fma(a, vt[c], p[c]);
  }
  const double LAM = 0.1 / 128.0;
#pragma unroll
  for (int c = 0; c < 8; ++c) p[c] = fma(-2.0, p[c], LAM);
  __syncthreads();  // staging reads done; sR switches to dbuf [row][j] layout

  // ---- ADMM loop: ONE barrier per iteration via rhs double-buffer.
  // Safety: all waves pass barrier_k before any wave writes rhs_{k+1} (to the
  // other buffer); reads of a buffer in iter k-2 complete before barrier_{k-1}.
  double z[8], u[8], r64[8];
#pragma unroll
  for (int c = 0; c < 8; ++c) { z[c] = 0.0; u[c] = 0.0; }

  for (int it = 0; it < NITER; ++it) {
    float* buf = sR + (it & 1) * BUFSZ;
    {
      float4 w0, w1;
      double rv;
      rv = (z[0] - u[0]) - p[0]; r64[0] = rv; w0.x = (float)rv;
      rv = (z[1] - u[1]) - p[1]; r64[1] = rv; w0.y = (float)rv;
      rv = (z[2] - u[2]) - p[2]; r64[2] = rv; w0.z = (float)rv;
      rv = (z[3] - u[3]) - p[3]; r64[3] = rv; w0.w = (float)rv;
      rv = (z[4] - u[4]) - p[4]; r64[4] = rv; w1.x = (float)rv;
      rv = (z[5] - u[5]) - p[5]; r64[5] = rv; w1.y = (float)rv;
      rv = (z[6] - u[6]) - p[6]; r64[6] = rv; w1.z = (float)rv;
      rv = (z[7] - u[7]) - p[7]; r64[7] = rv; w1.w = (float)rv;
      *(float4*)&buf[lane * RSTR + c0 + 0] = w0;
      *(float4*)&buf[lane * RSTR + c0 + 4] = w1;
    }
    __syncthreads();
    float acc[8];
#pragma unroll
    for (int c = 0; c < 8; ++c) acc[c] = 0.f;
#pragma unroll 4
    for (int j4 = 0; j4 < 32; ++j4) {
      const float4 a4 = *(const float4*)&buf[lane * RSTR + (j4 << 2)];
      const float* wp = Wtw + (j4 << 5);   // 32 consecutive floats: rows j4*4..+3
#pragma unroll
      for (int c = 0; c < 8; ++c) acc[c] = fmaf(a4.x, wp[c], acc[c]);
#pragma unroll
      for (int c = 0; c < 8; ++c) acc[c] = fmaf(a4.y, wp[8 + c], acc[c]);
#pragma unroll
      for (int c = 0; c < 8; ++c) acc[c] = fmaf(a4.z, wp[16 + c], acc[c]);
#pragma unroll
      for (int c = 0; c < 8; ++c) acc[c] = fmaf(a4.w, wp[24 + c], acc[c]);
    }
#pragma unroll
    for (int c = 0; c < 8; ++c) {
      const double x = r64[c] - (double)acc[c];
      const double y = x + u[c];
      const double zn = fmin(fmax(y, 0.0), 1.0);
      u[c] = y - zn;
      z[c] = zn;
    }
  }

  // ---- epilogue: threshold, row count k, coeffs (x 1/128 folded), out = coeffs . V
  double xb[8];
  double cnt = 0.0;
#pragma unroll
  for (int c = 0; c < 8; ++c) {
    xb[c] = (z[c] > 0.5) ? 1.0 : 0.0;
    cnt += xb[c];
  }
  sCnt[w * 64 + lane] = (float)cnt;
  __syncthreads();   // also guarantees all iter-49 buf reads complete
  double k = 0.0;
#pragma unroll
  for (int g = 0; g < 16; ++g) k += (double)sCnt[g * 64 + lane];
  const double rkS = (1.0 / 128.0) / (k + 1e-10);
  {
    float4 w0, w1;
    w0.x = (float)(xb[0] * rkS); w0.y = (float)(xb[1] * rkS);
    w0.z = (float)(xb[2] * rkS); w0.w = (float)(xb[3] * rkS);
    w1.x = (float)(xb[4] * rkS); w1.y = (float)(xb[5] * rkS);
    w1.z = (float)(xb[6] * rkS); w1.w = (float)(xb[7] * rkS);
    *(float4*)&sR[lane * RSTR + c0 + 0] = w0;   // buf0: iter-49 used buf1
    *(float4*)&sR[lane * RSTR + c0 + 4] = w1;
  }
  __syncthreads();

  float oa[8];
#pragma unroll
  for (int c = 0; c < 8; ++c) oa[c] = 0.f;
#pragma unroll 4
  for (int m4 = 0; m4 < 32; ++m4) {
    const float4 a4 = *(const float4*)&sR[lane * RSTR + (m4 << 2)];
    const float* v0 = Vc + ((m4 << 2) + 0) * 128;
    const float* v1 = Vc + ((m4 << 2) + 1) * 128;
    const float* v2 = Vc + ((m4 << 2) + 2) * 128;
    const float* v3 = Vc + ((m4 << 2) + 3) * 128;
#pragma unroll
    for (int c = 0; c < 8; ++c) oa[c] = fmaf(a4.x, v0[c], oa[c]);
#pragma unroll
    for (int c = 0; c < 8; ++c) oa[c] = fmaf(a4.y, v1[c], oa[c]);
#pragma unroll
    for (int c = 0; c < 8; ++c) oa[c] = fmaf(a4.z, v2[c], oa[c]);
#pragma unroll
    for (int c = 0; c < 8; ++c) oa[c] = fmaf(a4.w, v3[c], oa[c]);
  }
#pragma unroll
  for (int q = 0; q < 2; ++q) {
    float4 o;
    o.x = oa[q * 4 + 0]; o.y = oa[q * 4 + 1];
    o.z = oa[q * 4 + 2]; o.w = oa[q * 4 + 3];
    *(float4*)(outb + lane * 128 + c0 + q * 4) = o;
  }
}

// ---------------------------------------------------------------------------
extern "C" void kernel_launch(void* const* d_in, const int* in_sizes, int n_in,
                              void* d_out, int out_size, void* d_ws, size_t ws_size,
                              hipStream_t stream) {
  const float* Q = (const float*)d_in[0];
  const float* V = (const float*)d_in[1];
  float* out = (float*)d_out;
  double* ws = (double*)d_ws;
  double* Mw = ws;                // 1 MiB (M; recycled as Wt after NS)
  double* Xa = ws + 131072;
  double* Xb = ws + 262144;
  double* Tw = ws + 393216;       // NS temp; recycled as VsT64. total 4 MiB

  mk_m64<<<128, 256, 0, stream>>>(V, Mw, Xa);
  double* pa = Xa;
  double* pb = Xb;
  for (int i = 0; i < 3; ++i) {  // Newton-Schulz f64: residual ||E||^(2^(k+1)) ~ 6e-20
    ns_gemm64<<<128, 256, 0, stream>>>(pa, Mw, Tw, pa, 0);  // T = X*M
    ns_gemm64<<<128, 256, 0, stream>>>(Tw, pa, pb, pa, 1);  // X' = 2X - T*X
    double* tmp = pa; pa = pb; pb = tmp;
  }
  float* Wt = (float*)Mw;
  double* VsT64 = Tw;
  prep_aux<<<64, 256, 0, stream>>>(pa, V, Wt, VsT64);
  admm_corr<<<256, 1024, 0, stream>>>(Q, V, Wt, VsT64, out);
}

// Round 7
// 309.145 us; speedup vs baseline: 1.5438x; 1.5438x over previous
//
#include <hip/hip_runtime.h>

#define NBATCH 8
#define NROWS 2048
#define MDIM 128
#define NITER 50
#define PSTR 65     // Q^T staging stride (f32)
#define RSTR_R 136  // rhs limb row stride (bf16)
#define WSTR 104    // W LDS row stride (bf16), holds k=32..127
#define XSTR 132    // f32 overlay stride (xb / coeff)

// LDS byte offsets (single static block)
#define RH_B 0
#define RM_B 17408
#define RL_B 34816
#define WH_B 52224
#define WM_B 78848
#define WL_B 105472
#define CNT_B 132096
#define SMEM_BYTES 136192
#define PMAT_B 0       // overlay: 64x128 f64 (pre-loop only)
#define QST_B 68608    // overlay: Q^T staging (pre-loop only)
#define XB_B 0         // overlay: xb matrix (post-loop)
#define CF_B 36864     // overlay: coeff matrix (post-loop)

typedef unsigned short ushort_t;
typedef __attribute__((ext_vector_type(8))) short bf16x8;
typedef __attribute__((ext_vector_type(8))) unsigned short us8;
typedef __attribute__((ext_vector_type(4))) unsigned short us4;
typedef __attribute__((ext_vector_type(4))) float f32x4;

__device__ __host__ __forceinline__ ushort_t f2bf(float f) {
  unsigned int u = __builtin_bit_cast(unsigned int, f);
  unsigned int r = (u + 0x7fffu + ((u >> 16) & 1u)) >> 16;
  return (ushort_t)r;
}
__device__ __forceinline__ float bf2f(ushort_t h) {
  unsigned int u = ((unsigned int)h) << 16;
  return __builtin_bit_cast(float, u);
}

// ---------------------------------------------------------------------------
// mk_m64: M = I + 2*Vs*Vs^T (f64), X0 = 2I - M.  (unchanged, bit-identical)
// ---------------------------------------------------------------------------
__global__ __launch_bounds__(256) void mk_m64(const float* __restrict__ V,
                                              double* __restrict__ M,
                                              double* __restrict__ X0) {
  __shared__ double sA[32][130];
  __shared__ double sB[32][130];
  const int b = blockIdx.x >> 4, t = blockIdx.x & 15;
  const int i0 = (t >> 2) << 5, j0 = (t & 3) << 5;
  const float* Vb = V + b * MDIM * MDIM;
  const int tid = threadIdx.x;
  const double S = 1.0 / 128.0;
  for (int idx = tid; idx < 1024; idx += 256) {
    const int r = idx >> 5, c4 = (idx & 31) << 2;
    float4 v = *(const float4*)(Vb + (i0 + r) * MDIM + c4);
    sA[r][c4 + 0] = v.x * S; sA[r][c4 + 1] = v.y * S;
    sA[r][c4 + 2] = v.z * S; sA[r][c4 + 3] = v.w * S;
    float4 w = *(const float4*)(Vb + (j0 + r) * MDIM + c4);
    sB[r][c4 + 0] = w.x * S; sB[r][c4 + 1] = w.y * S;
    sB[r][c4 + 2] = w.z * S; sB[r][c4 + 3] = w.w * S;
  }
  __syncthreads();
  const int tx = tid & 15, ty = tid >> 4;
  double acc[2][2] = {};
  for (int k = 0; k < 128; ++k) {
    double a0 = sA[ty * 2 + 0][k], a1 = sA[ty * 2 + 1][k];
    double b0 = sB[tx * 2 + 0][k], b1 = sB[tx * 2 + 1][k];
    acc[0][0] = fma(a0, b0, acc[0][0]); acc[0][1] = fma(a0, b1, acc[0][1]);
    acc[1][0] = fma(a1, b0, acc[1][0]); acc[1][1] = fma(a1, b1, acc[1][1]);
  }
  double* Mb = M + b * 16384;
  double* Xb = X0 + b * 16384;
#pragma unroll
  for (int i = 0; i < 2; ++i)
#pragma unroll
    for (int j = 0; j < 2; ++j) {
      const int gi = i0 + ty * 2 + i, gj = j0 + tx * 2 + j;
      const double diag = (gi == gj) ? 1.0 : 0.0;
      const double mv = 2.0 * acc[i][j] + diag;
      Mb[gi * 128 + gj] = mv;
      Xb[gi * 128 + gj] = 2.0 * diag - mv;
    }
}

// ---------------------------------------------------------------------------
// ns_gemm64 (unchanged, bit-identical)
// ---------------------------------------------------------------------------
__global__ __launch_bounds__(256) void ns_gemm64(const double* __restrict__ A,
                                                 const double* __restrict__ B,
                                                 double* __restrict__ C,
                                                 const double* __restrict__ Xc,
                                                 int mode) {
  __shared__ double sA[32][130];
  __shared__ double sB[32][130];
  const int b = blockIdx.x >> 4, t = blockIdx.x & 15;
  const int i0 = (t >> 2) << 5, j0 = (t & 3) << 5;
  const double* Ab = A + b * 16384;
  const double* Bb = B + b * 16384;
  const int tid = threadIdx.x;
  for (int idx = tid; idx < 2048; idx += 256) {
    const int r = idx >> 6, c2 = (idx & 63) << 1;
    *(double2*)&sA[r][c2] = *(const double2*)(Ab + (i0 + r) * 128 + c2);
    *(double2*)&sB[r][c2] = *(const double2*)(Bb + (j0 + r) * 128 + c2);
  }
  __syncthreads();
  const int tx = tid & 15, ty = tid >> 4;
  double acc[2][2] = {};
  for (int k = 0; k < 128; ++k) {
    double a0 = sA[ty * 2 + 0][k], a1 = sA[ty * 2 + 1][k];
    double b0 = sB[tx * 2 + 0][k], b1 = sB[tx * 2 + 1][k];
    acc[0][0] = fma(a0, b0, acc[0][0]); acc[0][1] = fma(a0, b1, acc[0][1]);
    acc[1][0] = fma(a1, b0, acc[1][0]); acc[1][1] = fma(a1, b1, acc[1][1]);
  }
  double* Cb = C + b * 16384;
  const double* Xcb = Xc + b * 16384;
#pragma unroll
  for (int i = 0; i < 2; ++i)
#pragma unroll
    for (int j = 0; j < 2; ++j) {
      const int gi = i0 + ty * 2 + i, gj = j0 + tx * 2 + j;
      double v = acc[i][j];
      if (mode != 0) v = 2.0 * Xcb[gi * 128 + gj] - v;
      Cb[gi * 128 + gj] = v;
    }
}

// ---------------------------------------------------------------------------
// prep_aux: bf16 limb split of W^T (W = I - Minv; exact 3-way split of fp32 W),
// stored TRANSPOSED: Wxg[c*128 + j] = limb(W[j][c]) so A-frags read j-contiguous.
// Also VsT64[d][m] = f64 V[m][d]/128 (unchanged).
// ---------------------------------------------------------------------------
__global__ __launch_bounds__(256) void prep_aux(const double* __restrict__ Minv,
                                                const float* __restrict__ V,
                                                ushort_t* __restrict__ Whg,
                                                ushort_t* __restrict__ Wmg,
                                                ushort_t* __restrict__ Wlg,
                                                double* __restrict__ VsT64) {
  const int b = blockIdx.x >> 3, ch = blockIdx.x & 7;
  const double* Mb = Minv + b * 16384;
  const float* Vb = V + b * 16384;
  ushort_t* Whb = Whg + b * 16384;
  ushort_t* Wmb = Wmg + b * 16384;
  ushort_t* Wlb = Wlg + b * 16384;
  double* Tb = VsT64 + b * 16384;
  const int base = ch * 2048;
  for (int k = threadIdx.x; k < 2048; k += 256) {
    const int idx = base + k;
    const int j = idx >> 7, c = idx & 127;
    const double diag = (j == c) ? 1.0 : 0.0;
    const float wf = (float)(diag - Mb[idx]);      // same fp32 W bits as R5
    const ushort_t h = f2bf(wf);
    const float r1 = wf - bf2f(h);
    const ushort_t m_ = f2bf(r1);
    const float r2 = r1 - bf2f(m_);
    const ushort_t l_ = f2bf(r2);
    Whb[c * 128 + j] = h;    // transposed store
    Wmb[c * 128 + j] = m_;
    Wlb[c * 128 + j] = l_;
    Tb[idx] = (double)Vb[c * 128 + j] * (1.0 / 128.0);
  }
}

// ---------------------------------------------------------------------------
// admm_mfma: persistent ADMM, f64 state + exact-split bf16 MFMA correction.
// grid 256, b = blockIdx&7 (XCD-aligned), 1024 threads = 16 waves.
// corr^T = W * rhs^T via mfma_f32_16x16x32_bf16, 6 limb pairs (hH,hM,mH,mM,hL,lH).
// Wave w: A row-tile ct=w&7 (c-dim), B col-tiles nh=w>>3 -> 2 n-tiles.
// A (W limbs): ks0 resident in VGPRs (from global), ks1-3 from LDS.
// B (rhs limbs): rebuilt in LDS each iter (thread writes 4 contiguous bf16 = b64).
// f64 state/P/epilogue chains identical to R5.
// ---------------------------------------------------------------------------
__global__ __launch_bounds__(1024) void admm_mfma(const float* __restrict__ Q,
                                                  const float* __restrict__ V,
                                                  const ushort_t* __restrict__ Whg,
                                                  const ushort_t* __restrict__ Wmg,
                                                  const ushort_t* __restrict__ Wlg,
                                                  const double* __restrict__ VsT64,
                                                  float* __restrict__ out) {
  __shared__ __align__(16) char smem[SMEM_BYTES];
  const int tid = threadIdx.x;
  const int b = blockIdx.x & 7;
  const int n0 = (blockIdx.x >> 3) << 6;
  const int lane = tid & 63;
  const int w = tid >> 6;              // 0..15
  const int c0_old = w << 3;           // old-mapping col base (P + epilogue)
  const int c0u = __builtin_amdgcn_readfirstlane(c0_old);
  const int quad = lane >> 4, col16 = lane & 15;
  const int ct = w & 7, nh = w >> 3;
  const int rowA = ct * 16 + col16;            // A-frag m-index (c-dim)
  const int nrow0 = (nh * 2 + 0) * 16 + col16; // B-frag n-index, tile 0
  const int nrow1 = (nh * 2 + 1) * 16 + col16; // tile 1
  const int cbase = ct * 16 + quad * 4;        // C row base (c-dim)

  const float* Qb = Q + ((size_t)(b * NROWS + n0)) * MDIM;
  const double* Vtc = VsT64 + b * 16384 + c0u;
  const float* Vc = V + b * 16384 + c0u;
  float* outb = out + ((size_t)(b * NROWS + n0)) * MDIM;
  const ushort_t* WG0 = Whg + b * 16384;
  const ushort_t* WG1 = Wmg + b * 16384;
  const ushort_t* WG2 = Wlg + b * 16384;

  float* QST = (float*)(smem + QST_B);
  double* pmat = (double*)(smem + PMAT_B);
  ushort_t* rhp = (ushort_t*)(smem + RH_B);
  ushort_t* rmp = (ushort_t*)(smem + RM_B);
  ushort_t* rlp = (ushort_t*)(smem + RL_B);
  ushort_t* wh = (ushort_t*)(smem + WH_B);
  ushort_t* wm = (ushort_t*)(smem + WM_B);
  ushort_t* wl = (ushort_t*)(smem + WL_B);
  float* sCnt = (float*)(smem + CNT_B);

  // ---- Phase 1: stage Q^T (f32): QST[d*65 + r]
  for (int idx = tid; idx < 2048; idx += 1024) {
    const int r = idx >> 5, d4 = (idx & 31) << 2;
    const float4 q = *(const float4*)(Qb + r * 128 + d4);
    QST[(d4 + 0) * PSTR + r] = q.x;
    QST[(d4 + 1) * PSTR + r] = q.y;
    QST[(d4 + 2) * PSTR + r] = q.z;
    QST[(d4 + 3) * PSTR + r] = q.w;
  }
  __syncthreads();

  // ---- Phase 2: P = -2 Q Vs^T + lam/m (f64, chain identical to R5)
  double p8[8];
#pragma unroll
  for (int c = 0; c < 8; ++c) p8[c] = 0.0;
  for (int d = 0; d < 128; ++d) {
    const double a = (double)QST[d * PSTR + lane];
    const double* vt = Vtc + d * 128;
#pragma unroll
    for (int c = 0; c < 8; ++c) p8[c] = fma(a, vt[c], p8[c]);
  }
  const double LAM = 0.1 / 128.0;
#pragma unroll
  for (int c = 0; c < 8; ++c) p8[c] = fma(-2.0, p8[c], LAM);
  __syncthreads();  // QST reads done (pmat overlays a disjoint region anyway)
#pragma unroll
  for (int c = 0; c < 8; ++c) pmat[lane * 128 + c0_old + c] = p8[c];
  __syncthreads();

  // ---- Phase 3: redistribute P into MFMA C-layout positions
  double pC[2][4];
#pragma unroll
  for (int i = 0; i < 4; ++i) {
    pC[0][i] = pmat[nrow0 * 128 + cbase + i];
    pC[1][i] = pmat[nrow1 * 128 + cbase + i];
  }
  __syncthreads();  // pmat dead

  // ---- Phase 4: stage W limbs k=32..127 into LDS; ks0 frags into VGPRs
  {
    const ushort_t* wg[3] = {WG0, WG1, WG2};
    ushort_t* wd[3] = {wh, wm, wl};
#pragma unroll
    for (int L = 0; L < 3; ++L)
      for (int idx = tid; idx < 1536; idx += 1024) {
        const int c = idx / 12, t8 = idx - c * 12;
        *(us8*)(wd[L] + c * WSTR + t8 * 8) =
            *(const us8*)(wg[L] + c * 128 + 32 + t8 * 8);
      }
  }
  bf16x8 wf0h = *(const bf16x8*)(WG0 + rowA * 128 + quad * 8);
  bf16x8 wf0m = *(const bf16x8*)(WG1 + rowA * 128 + quad * 8);
  bf16x8 wf0l = *(const bf16x8*)(WG2 + rowA * 128 + quad * 8);
  __syncthreads();

  // ---- ADMM loop
  double z[2][4], u[2][4];
#pragma unroll
  for (int t = 0; t < 2; ++t)
#pragma unroll
    for (int i = 0; i < 4; ++i) { z[t][i] = 0.0; u[t][i] = 0.0; }

  for (int it = 0; it < NITER; ++it) {
    // split r -> 3 bf16 limbs, write to LDS (b64 each)
#pragma unroll
    for (int t = 0; t < 2; ++t) {
      const int nr = t ? nrow1 : nrow0;
      us4 hh, mm2, ll;
#pragma unroll
      for (int i = 0; i < 4; ++i) {
        const double rv = (z[t][i] - u[t][i]) - pC[t][i];
        const float rf = (float)rv;
        const ushort_t h = f2bf(rf);
        const float r1 = rf - bf2f(h);
        const ushort_t m_ = f2bf(r1);
        const float r2 = r1 - bf2f(m_);
        const ushort_t l_ = f2bf(r2);
        hh[i] = h; mm2[i] = m_; ll[i] = l_;
      }
      *(us4*)(rhp + nr * RSTR_R + cbase) = hh;
      *(us4*)(rmp + nr * RSTR_R + cbase) = mm2;
      *(us4*)(rlp + nr * RSTR_R + cbase) = ll;
    }
    __syncthreads();

    f32x4 acc0 = {0.f, 0.f, 0.f, 0.f};
    f32x4 acc1 = {0.f, 0.f, 0.f, 0.f};
#pragma unroll
    for (int ks = 0; ks < 4; ++ks) {
      bf16x8 ah, am2, al2;
      if (ks == 0) {
        ah = wf0h; am2 = wf0m; al2 = wf0l;
      } else {
        const int ko = (ks - 1) * 32 + quad * 8;
        ah  = *(const bf16x8*)(wh + rowA * WSTR + ko);
        am2 = *(const bf16x8*)(wm + rowA * WSTR + ko);
        al2 = *(const bf16x8*)(wl + rowA * WSTR + ko);
      }
      const int kq = ks * 32 + quad * 8;
      const bf16x8 b0h = *(const bf16x8*)(rhp + nrow0 * RSTR_R + kq);
      const bf16x8 b0m = *(const bf16x8*)(rmp + nrow0 * RSTR_R + kq);
      const bf16x8 b0l = *(const bf16x8*)(rlp + nrow0 * RSTR_R + kq);
      const bf16x8 b1h = *(const bf16x8*)(rhp + nrow1 * RSTR_R + kq);
      const bf16x8 b1m = *(const bf16x8*)(rmp + nrow1 * RSTR_R + kq);
      const bf16x8 b1l = *(const bf16x8*)(rlp + nrow1 * RSTR_R + kq);
      acc0 = __builtin_amdgcn_mfma_f32_16x16x32_bf16(ah,  b0h, acc0, 0, 0, 0);
      acc0 = __builtin_amdgcn_mfma_f32_16x16x32_bf16(ah,  b0m, acc0, 0, 0, 0);
      acc0 = __builtin_amdgcn_mfma_f32_16x16x32_bf16(am2, b0h, acc0, 0, 0, 0);
      acc0 = __builtin_amdgcn_mfma_f32_16x16x32_bf16(am2, b0m, acc0, 0, 0, 0);
      acc0 = __builtin_amdgcn_mfma_f32_16x16x32_bf16(ah,  b0l, acc0, 0, 0, 0);
      acc0 = __builtin_amdgcn_mfma_f32_16x16x32_bf16(al2, b0h, acc0, 0, 0, 0);
      acc1 = __builtin_amdgcn_mfma_f32_16x16x32_bf16(ah,  b1h, acc1, 0, 0, 0);
      acc1 = __builtin_amdgcn_mfma_f32_16x16x32_bf16(ah,  b1m, acc1, 0, 0, 0);
      acc1 = __builtin_amdgcn_mfma_f32_16x16x32_bf16(am2, b1h, acc1, 0, 0, 0);
      acc1 = __builtin_amdgcn_mfma_f32_16x16x32_bf16(am2, b1m, acc1, 0, 0, 0);
      acc1 = __builtin_amdgcn_mfma_f32_16x16x32_bf16(ah,  b1l, acc1, 0, 0, 0);
      acc1 = __builtin_amdgcn_mfma_f32_16x16x32_bf16(al2, b1h, acc1, 0, 0, 0);
    }
    __syncthreads();  // all rhs reads done before next iteration's writes

#pragma unroll
    for (int t = 0; t < 2; ++t)
#pragma unroll
      for (int i = 0; i < 4; ++i) {
        const float corr = (t == 0) ? acc0[i] : acc1[i];
        const double rv = (z[t][i] - u[t][i]) - pC[t][i];  // recompute (bit-identical)
        const double x = rv - (double)corr;
        const double y = x + u[t][i];
        const double zn = fmin(fmax(y, 0.0), 1.0);
        u[t][i] = y - zn;
        z[t][i] = zn;
      }
  }

  // ---- epilogue: threshold in C-layout (f64 compare), xb -> LDS matrix
  float* xbm = (float*)(smem + XB_B);
#pragma unroll
  for (int t = 0; t < 2; ++t) {
    const int nr = t ? nrow1 : nrow0;
    float4 o;
    o.x = (z[t][0] > 0.5) ? 1.f : 0.f;
    o.y = (z[t][1] > 0.5) ? 1.f : 0.f;
    o.z = (z[t][2] > 0.5) ? 1.f : 0.f;
    o.w = (z[t][3] > 0.5) ? 1.f : 0.f;
    *(float4*)(xbm + nr * XSTR + cbase) = o;
  }
  __syncthreads();

  // ---- old-mapping epilogue (R5 chain): counts, coeffs, out = coeffs . V
  float xb8[8];
  {
    const float4 a = *(const float4*)(xbm + lane * XSTR + c0_old + 0);
    const float4 c2 = *(const float4*)(xbm + lane * XSTR + c0_old + 4);
    xb8[0] = a.x; xb8[1] = a.y; xb8[2] = a.z; xb8[3] = a.w;
    xb8[4] = c2.x; xb8[5] = c2.y; xb8[6] = c2.z; xb8[7] = c2.w;
  }
  double cnt = 0.0;
#pragma unroll
  for (int c = 0; c < 8; ++c) cnt += (double)xb8[c];
  sCnt[w * 64 + lane] = (float)cnt;
  __syncthreads();
  double k = 0.0;
#pragma unroll
  for (int g = 0; g < 16; ++g) k += (double)sCnt[g * 64 + lane];
  const double rkS = (1.0 / 128.0) / (k + 1e-10);
  float* cf = (float*)(smem + CF_B);
  {
    float4 w0, w1;
    w0.x = (float)((double)xb8[0] * rkS); w0.y = (float)((double)xb8[1] * rkS);
    w0.z = (float)((double)xb8[2] * rkS); w0.w = (float)((double)xb8[3] * rkS);
    w1.x = (float)((double)xb8[4] * rkS); w1.y = (float)((double)xb8[5] * rkS);
    w1.z = (float)((double)xb8[6] * rkS); w1.w = (float)((double)xb8[7] * rkS);
    *(float4*)(cf + lane * XSTR + c0_old + 0) = w0;
    *(float4*)(cf + lane * XSTR + c0_old + 4) = w1;
  }
  __syncthreads();

  float oa[8];
#pragma unroll
  for (int c = 0; c < 8; ++c) oa[c] = 0.f;
#pragma unroll 4
  for (int m4 = 0; m4 < 32; ++m4) {
    const float4 a4 = *(const float4*)(cf + lane * XSTR + (m4 << 2));
    const float* v0 = Vc + ((m4 << 2) + 0) * 128;
    const float* v1 = Vc + ((m4 << 2) + 1) * 128;
    const float* v2 = Vc + ((m4 << 2) + 2) * 128;
    const float* v3 = Vc + ((m4 << 2) + 3) * 128;
#pragma unroll
    for (int c = 0; c < 8; ++c) oa[c] = fmaf(a4.x, v0[c], oa[c]);
#pragma unroll
    for (int c = 0; c < 8; ++c) oa[c] = fmaf(a4.y, v1[c], oa[c]);
#pragma unroll
    for (int c = 0; c < 8; ++c) oa[c] = fmaf(a4.z, v2[c], oa[c]);
#pragma unroll
    for (int c = 0; c < 8; ++c) oa[c] = fmaf(a4.w, v3[c], oa[c]);
  }
#pragma unroll
  for (int q = 0; q < 2; ++q) {
    float4 o;
    o.x = oa[q * 4 + 0]; o.y = oa[q * 4 + 1];
    o.z = oa[q * 4 + 2]; o.w = oa[q * 4 + 3];
    *(float4*)(outb + lane * 128 + c0_old + q * 4) = o;
  }
}

// ---------------------------------------------------------------------------
extern "C" void kernel_launch(void* const* d_in, const int* in_sizes, int n_in,
                              void* d_out, int out_size, void* d_ws, size_t ws_size,
                              hipStream_t stream) {
  const float* Q = (const float*)d_in[0];
  const float* V = (const float*)d_in[1];
  float* out = (float*)d_out;
  double* ws = (double*)d_ws;
  double* Mw = ws;                // 1 MiB: M; recycled as bf16 W-limb arrays
  double* Xa = ws + 131072;
  double* Xb = ws + 262144;
  double* Tw = ws + 393216;       // NS temp; recycled as VsT64

  mk_m64<<<128, 256, 0, stream>>>(V, Mw, Xa);
  double* pa = Xa;
  double* pb = Xb;
  for (int i = 0; i < 3; ++i) {  // Newton-Schulz f64: residual ~6e-20
    ns_gemm64<<<128, 256, 0, stream>>>(pa, Mw, Tw, pa, 0);  // T = X*M
    ns_gemm64<<<128, 256, 0, stream>>>(Tw, pa, pb, pa, 1);  // X' = 2X - T*X
    double* tmp = pa; pa = pb; pb = tmp;
  }
  // recycle Mw bytes as the three bf16 limb arrays (8*16384 ushorts each)
  ushort_t* Whg = (ushort_t*)Mw;
  ushort_t* Wmg = Whg + 131072;
  ushort_t* Wlg = Whg + 262144;
  double* VsT64 = Tw;
  prep_aux<<<64, 256, 0, stream>>>(pa, V, Whg, Wmg, Wlg, VsT64);
  admm_mfma<<<256, 1024, 0, stream>>>(Q, V, Whg, Wmg, Wlg, VsT64, out);
}